// Round 1
// baseline (394.908 us; speedup 1.0000x reference)
//
#include <hip/hip_runtime.h>
#include <hip/hip_bf16.h>

// GCN R4: barrier-free-K GEMM. B col-tile (128x256 bf16 = 64KB, staged in two
// 32KB halves) lives entirely in LDS in frag-major order; A fragments load
// straight from global (no A staging, no per-K-step barriers). Everything
// else (8x-replicated CSR hist/scan/scatter, spmm) unchanged from R3.

#define N_NODES 50000
#define N_EDGES 800000
#define KDIM 256
#define REP 8
#define NC (N_NODES * REP)            // 400000 replicated counters
#define NB2 ((NC + 1023) / 1024)      // 391 scan blocks
#define NC_PAD (NB2 * 1024)           // 400384

typedef __attribute__((ext_vector_type(8))) short short8;
typedef __attribute__((ext_vector_type(4))) float f32x4;

__device__ __forceinline__ ushort f2bf(float f) {
    union { float f; unsigned u; } x; x.f = f;
    unsigned r = x.u + 0x7fffu + ((x.u >> 16) & 1u);  // RTN-even
    return (ushort)(r >> 16);
}
__device__ __forceinline__ float bf2f(ushort u) {
    union { unsigned u; float f; } x; x.u = ((unsigned)u) << 16;
    return x.f;
}

// ---------------- merged weight transpose-casts ----------------
// Wt[n*256 + k] = bf16(W[k*N + n]) for W1(256x256), W2(256x256), W3(256x128)
__global__ __launch_bounds__(256) void transpose_all_kernel(
        const float* __restrict__ W1, const float* __restrict__ W2,
        const float* __restrict__ W3, ushort* __restrict__ Wt1,
        ushort* __restrict__ Wt2, ushort* __restrict__ Wt3) {
    int id = blockIdx.x * blockDim.x + threadIdx.x;
    if (id < 65536) {
        int n = id >> 8, k = id & 255;
        Wt1[n * 256 + k] = f2bf(W1[k * 256 + n]);
    } else if (id < 131072) {
        int i = id - 65536, n = i >> 8, k = i & 255;
        Wt2[n * 256 + k] = f2bf(W2[k * 256 + n]);
    } else if (id < 163840) {
        int i = id - 131072, n = i >> 8, k = i & 255;
        Wt3[n * 256 + k] = f2bf(W3[k * 128 + n]);
    }
}

// ---------------- GEMM body: C[M,N] = A[M,256] @ Wt[N,256]^T, bf16 out ------
// 128x128 tile, 256 threads = 4 waves (2x2 of 64x64), 16x16x32 MFMA.
// B staged in LDS frag-major: slot s (16B units) decodes as
//   mi = s&15, q = (s>>4)&3, kb = (s>>6)&3, g = s>>8
//   element: col = g*16+mi, k = kbase + kb*32 + q*8
// A wave's fragment read for (g, kb) is slots [(g*4+kb)*64 + lane]:
// 64 lanes x 16B contiguous -> conflict-free ds_read_b128.

template <bool AFP32>
__device__ __forceinline__ void gemm_body(
        const void* __restrict__ Ain, const ushort* __restrict__ Wt,
        ushort* __restrict__ C, int M, int N, int bx, int by) {
    __shared__ ushort Ws[2048 * 8];   // 32 KB: half-K (128) of the B col-tile

    int t = threadIdx.x;
    int lane = t & 63;
    int w = t >> 6;
    int row0 = bx * 128, col0 = by * 128;
    int wm = (w & 1) * 64, wn = (w >> 1) * 64;
    int q = lane >> 4, mi = lane & 15;

    const ushort* Ab = (const ushort*)Ain;
    const float*  Af = (const float*)Ain;

    f32x4 acc[4][4];
    #pragma unroll
    for (int i = 0; i < 4; i++)
        #pragma unroll
        for (int j = 0; j < 4; j++) acc[i][j] = (f32x4)0.f;

    for (int half = 0; half < 2; half++) {
        int kbase = half * 128;
        if (half) __syncthreads();    // drain readers before Ws reuse
        // stage 32KB of B, frag-major; wave w covers kb=w, iter i covers g=i:
        // global pattern = 16 cols x 64B contiguous chunks (L2-resident Wt)
        #pragma unroll
        for (int i = 0; i < 8; i++) {
            int s = i * 256 + t;
            int scol = ((s >> 8) << 4) | (s & 15);               // g*16 + mi
            int sk   = kbase + ((s >> 6) & 3) * 32 + ((s >> 4) & 3) * 8;
            *(short8*)&Ws[s * 8] =
                *(const short8*)&Wt[(size_t)(col0 + scol) * KDIM + sk];
        }
        __syncthreads();

        #pragma unroll
        for (int kb = 0; kb < 4; kb++) {
            int k0 = kbase + kb * 32;
            short8 af[4], bfr[4];
            #pragma unroll
            for (int mt = 0; mt < 4; mt++) {
                int ga = row0 + wm + mt * 16 + mi;
                if (ga >= M) ga = M - 1;
                if (AFP32) {
                    float4 f0 = *(const float4*)&Af[(size_t)ga * KDIM + k0 + q * 8];
                    float4 f1 = *(const float4*)&Af[(size_t)ga * KDIM + k0 + q * 8 + 4];
                    af[mt][0] = (short)f2bf(f0.x); af[mt][1] = (short)f2bf(f0.y);
                    af[mt][2] = (short)f2bf(f0.z); af[mt][3] = (short)f2bf(f0.w);
                    af[mt][4] = (short)f2bf(f1.x); af[mt][5] = (short)f2bf(f1.y);
                    af[mt][6] = (short)f2bf(f1.z); af[mt][7] = (short)f2bf(f1.w);
                } else {
                    af[mt] = *(const short8*)&Ab[(size_t)ga * KDIM + k0 + q * 8];
                }
            }
            #pragma unroll
            for (int nt = 0; nt < 4; nt++) {
                int g = (wn >> 4) + nt;
                bfr[nt] = *(const short8*)&Ws[((g * 4 + kb) * 64 + lane) * 8];
            }
            #pragma unroll
            for (int mt = 0; mt < 4; mt++)
                #pragma unroll
                for (int nt = 0; nt < 4; nt++)
                    acc[mt][nt] = __builtin_amdgcn_mfma_f32_16x16x32_bf16(
                        af[mt], bfr[nt], acc[mt][nt], 0, 0, 0);
        }
    }

    // C/D layout: col = lane&15, row = q*4 + reg
    #pragma unroll
    for (int mt = 0; mt < 4; mt++) {
        #pragma unroll
        for (int r = 0; r < 4; r++) {
            int grow = row0 + wm + mt * 16 + q * 4 + r;
            if (grow < M) {
                #pragma unroll
                for (int nt = 0; nt < 4; nt++) {
                    int gcol = col0 + wn + nt * 16 + mi;
                    C[grow * N + gcol] = f2bf(acc[mt][nt][r]);
                }
            }
        }
    }
}

// layer-1 gemm (fp32 A, fused cast) + hist in one fat kernel.
// blocks [0, GB1): gemm tiles; blocks [GB1, GB1+3125): hist.
#define GB1 782   // 391 row-tiles x 2 col-tiles

__global__ __launch_bounds__(256) void gemm1_hist_kernel(
        const float* __restrict__ x, const ushort* __restrict__ Wt1,
        ushort* __restrict__ C, const int* __restrict__ rows,
        int* __restrict__ counts) {
    int b = blockIdx.x;
    if (b < GB1) {
        gemm_body<true>(x, Wt1, C, N_NODES, 256, b % 391, b / 391);
    } else {
        int e = (b - GB1) * 256 + threadIdx.x;
        if (e < N_EDGES) {
            int r = rows[e];
            atomicAdd(&counts[(r << 3) | (e & 7)], 1);
        }
    }
}

template <bool AFP32>
__global__ __launch_bounds__(256) void gemm_bf16_kernel(
        const void* __restrict__ Ain, const ushort* __restrict__ Wt,
        ushort* __restrict__ C, int M, int N) {
    gemm_body<AFP32>(Ain, Wt, C, M, N, blockIdx.x, blockIdx.y);
}

// ---------------- hierarchical scan over NC replicated counters ------------

__global__ __launch_bounds__(256) void scan_sums(const int* __restrict__ counts,
                                                 int* __restrict__ bsum) {
    __shared__ int ws[4];
    int b = blockIdx.x, t = threadIdx.x, lane = t & 63, wv = t >> 6;
    int4 v = *(const int4*)&counts[b * 1024 + t * 4];
    int s = v.x + v.y + v.z + v.w;
    #pragma unroll
    for (int off = 32; off >= 1; off >>= 1) s += __shfl_down(s, off, 64);
    if (lane == 0) ws[wv] = s;
    __syncthreads();
    if (t == 0) bsum[b] = ws[0] + ws[1] + ws[2] + ws[3];
}

// single block, 512 threads: exclusive scan of NB2 block sums; writes total.
__global__ __launch_bounds__(512) void scan_block(const int* __restrict__ bsum,
                                                  int* __restrict__ boff,
                                                  int* __restrict__ rp8, int nb) {
    __shared__ int ws[8];
    int t = threadIdx.x, lane = t & 63, wv = t >> 6;
    int v = (t < nb) ? bsum[t] : 0;
    int incl = v;
    #pragma unroll
    for (int off = 1; off < 64; off <<= 1) {
        int u = __shfl_up(incl, off, 64);
        if (lane >= off) incl += u;
    }
    if (lane == 63) ws[wv] = incl;
    __syncthreads();
    int wo = 0;
    #pragma unroll
    for (int j = 0; j < 7; j++) wo += (j < wv) ? ws[j] : 0;
    if (t < nb) boff[t] = wo + incl - v;
    if (t == 511) rp8[NC] = wo + incl;   // == N_EDGES
}

__global__ __launch_bounds__(256) void scan_apply(int* __restrict__ counts,
                                                  const int* __restrict__ boff,
                                                  int* __restrict__ rp8) {
    __shared__ int ws[4];
    int b = blockIdx.x, t = threadIdx.x, lane = t & 63, wv = t >> 6;
    int i = b * 1024 + t * 4;
    int4 v = *(const int4*)&counts[i];
    int s0 = v.x, s01 = s0 + v.y, s012 = s01 + v.z, tsum = s012 + v.w;
    int incl = tsum;
    #pragma unroll
    for (int off = 1; off < 64; off <<= 1) {
        int u = __shfl_up(incl, off, 64);
        if (lane >= off) incl += u;
    }
    if (lane == 63) ws[wv] = incl;
    __syncthreads();
    int woff = 0;
    #pragma unroll
    for (int j = 0; j < 3; j++) woff += (j < wv) ? ws[j] : 0;
    int base = boff[b] + woff + incl - tsum;
    if (i < NC)     rp8[i]     = base;
    if (i + 1 < NC) rp8[i + 1] = base + s0;
    if (i + 2 < NC) rp8[i + 2] = base + s01;
    if (i + 3 < NC) rp8[i + 3] = base + s012;
    *(int4*)&counts[i] = make_int4(0, 0, 0, 0);
}

__global__ void scatter_kernel(const int* __restrict__ rows, const int* __restrict__ cols,
                               const float* __restrict__ vals, const int* __restrict__ rp8,
                               int* __restrict__ counts, int2* __restrict__ cv) {
    int e = blockIdx.x * blockDim.x + threadIdx.x;
    if (e < N_EDGES) {
        int idx = (rows[e] << 3) | (e & 7);
        int pos = rp8[idx] + atomicAdd(&counts[idx], 1);
        cv[pos] = make_int2(cols[e], __float_as_int(vals[e]));
    }
}

// ---------------- SpMM (CSR): wave per row, EP edge-groups x 4 unroll ------
// Lane = ep*FL + fl; each ep group owns 4 contiguous edges per iteration ->
// 4 independent 16B gathers + 4 int2 meta loads in flight per lane.

template <int F, bool RELU, bool OUT_BF16>
__global__ __launch_bounds__(256) void spmm_kernel(
        const ushort* __restrict__ H, const int* __restrict__ rp8,
        const int2* __restrict__ cv, const float* __restrict__ bias,
        void* __restrict__ out, int nrows) {
    constexpr int FL = F / 8;       // 32 (F=256) / 16 (F=128)
    constexpr int EP = 64 / FL;     // 2 / 4
    constexpr int STEP = EP * 4;    // 8 / 16 edges per iteration
    int wave = threadIdx.x >> 6, lane = threadIdx.x & 63;
    int r = blockIdx.x * 4 + wave;
    if (r >= nrows) return;
    int fl = lane % FL, ep = lane / FL;
    const ushort* Hl = H + fl * 8;

    float acc[8];
    #pragma unroll
    for (int j = 0; j < 8; j++) acc[j] = 0.f;

    int start = rp8[r * REP], end = rp8[r * REP + REP];
    for (int base = start; base < end; base += STEP) {
        int e0 = base + ep * 4;
        int2 m0 = cv[e0], m1 = cv[e0 + 1], m2 = cv[e0 + 2], m3 = cv[e0 + 3];
        int   c0 = (e0     < end) ? m0.x : 0;
        int   c1 = (e0 + 1 < end) ? m1.x : 0;
        int   c2 = (e0 + 2 < end) ? m2.x : 0;
        int   c3 = (e0 + 3 < end) ? m3.x : 0;
        float v0 = (e0     < end) ? __int_as_float(m0.y) : 0.f;
        float v1 = (e0 + 1 < end) ? __int_as_float(m1.y) : 0.f;
        float v2 = (e0 + 2 < end) ? __int_as_float(m2.y) : 0.f;
        float v3 = (e0 + 3 < end) ? __int_as_float(m3.y) : 0.f;
        short8 h0 = *(const short8*)&Hl[(size_t)c0 * F];
        short8 h1 = *(const short8*)&Hl[(size_t)c1 * F];
        short8 h2 = *(const short8*)&Hl[(size_t)c2 * F];
        short8 h3 = *(const short8*)&Hl[(size_t)c3 * F];
        #pragma unroll
        for (int j = 0; j < 8; j++)
            acc[j] += v0 * bf2f((ushort)h0[j]) + v1 * bf2f((ushort)h1[j])
                    + v2 * bf2f((ushort)h2[j]) + v3 * bf2f((ushort)h3[j]);
    }

    #pragma unroll
    for (int off = FL; off < 64; off <<= 1)
        #pragma unroll
        for (int j = 0; j < 8; j++) acc[j] += __shfl_down(acc[j], off, 64);

    if (ep == 0) {
        #pragma unroll
        for (int j = 0; j < 8; j++) {
            float o = acc[j] + bias[fl * 8 + j];
            if (RELU) o = fmaxf(o, 0.f);
            acc[j] = o;
        }
        if (OUT_BF16) {
            short8 ob;
            #pragma unroll
            for (int j = 0; j < 8; j++) ob[j] = (short)f2bf(acc[j]);
            *(short8*)((ushort*)out + (size_t)r * F + fl * 8) = ob;
        } else {
            float* of = (float*)out + (size_t)r * F + fl * 8;
            *(float4*)&of[0] = make_float4(acc[0], acc[1], acc[2], acc[3]);
            *(float4*)&of[4] = make_float4(acc[4], acc[5], acc[6], acc[7]);
        }
    }
}

// ---------------- launch ----------------

extern "C" void kernel_launch(void* const* d_in, const int* in_sizes, int n_in,
                              void* d_out, int out_size, void* d_ws, size_t ws_size,
                              hipStream_t stream) {
    const float* x    = (const float*)d_in[0];
    const float* av   = (const float*)d_in[1];
    const int*   rows = (const int*)d_in[2];
    const int*   cols = (const int*)d_in[3];
    const float* W1   = (const float*)d_in[4];
    const float* b1   = (const float*)d_in[5];
    const float* W2   = (const float*)d_in[6];
    const float* b2   = (const float*)d_in[7];
    const float* W3   = (const float*)d_in[8];
    const float* b3   = (const float*)d_in[9];
    float* out = (float*)d_out;

    const int N = N_NODES, E = N_EDGES;

    char* p = (char*)d_ws;
    auto carve = [&](size_t bytes) {
        void* q = (void*)p;
        p += (bytes + 255) & ~(size_t)255;
        return q;
    };
    ushort* bufG = (ushort*)carve((size_t)N * 256 * 2);
    ushort* bufH = (ushort*)carve((size_t)N * 256 * 2);
    ushort* Wt1  = (ushort*)carve((size_t)256 * 256 * 2);
    ushort* Wt2  = (ushort*)carve((size_t)256 * 256 * 2);
    ushort* Wt3  = (ushort*)carve((size_t)128 * 256 * 2);
    int*    rp8    = (int*)carve((size_t)(NC + 1) * 4);
    int*    counts = (int*)carve((size_t)NC_PAD * 4);
    int*    bsum   = (int*)carve((size_t)NB2 * 4);
    int*    boff   = (int*)carve((size_t)NB2 * 4);
    int2*   cv     = (int2*)carve((size_t)(E + 16) * 8);

    hipMemsetAsync(counts, 0, (size_t)NC_PAD * 4, stream);
    transpose_all_kernel<<<(163840 + 255) / 256, 256, 0, stream>>>(W1, W2, W3, Wt1, Wt2, Wt3);

    // layer-1 gemm (latency-optimized) overlapped with hist (latency-bound)
    gemm1_hist_kernel<<<GB1 + (E + 255) / 256, 256, 0, stream>>>(x, Wt1, bufG, rows, counts);

    scan_sums<<<NB2, 256, 0, stream>>>(counts, bsum);
    scan_block<<<1, 512, 0, stream>>>(bsum, boff, rp8, NB2);
    scan_apply<<<NB2, 256, 0, stream>>>(counts, boff, rp8);
    scatter_kernel<<<(E + 255) / 256, 256, 0, stream>>>(rows, cols, av, rp8, counts, cv);

    int spmm_blocks = (N + 3) / 4;
    spmm_kernel<256, true, true><<<spmm_blocks, 256, 0, stream>>>(bufG, rp8, cv, b1, bufH, N);
    gemm_bf16_kernel<false><<<dim3(391, 2), 256, 0, stream>>>(bufH, Wt2, bufG, N, 256);
    spmm_kernel<256, true, true><<<spmm_blocks, 256, 0, stream>>>(bufG, rp8, cv, b2, bufH, N);
    gemm_bf16_kernel<false><<<dim3(391, 1), 256, 0, stream>>>(bufH, Wt3, bufG, N, 128);
    spmm_kernel<128, false, false><<<spmm_blocks, 256, 0, stream>>>(bufG, rp8, cv, b3, out, N);
}

// Round 2
// 371.836 us; speedup vs baseline: 1.0620x; 1.0620x over previous
//
#include <hip/hip_runtime.h>
#include <hip/hip_bf16.h>

// GCN R5: 2-phase pipelined GEMM with global_load_lds (width=16) and
// frag-major LDS via pre-permuted per-lane global source addresses
// (LDS dest stays linear: wave-uniform base + lane*16). One barrier per
// K-step; loads for step k+1 fly during MFMA of step k. LDS-staged C
// epilogue emits 256B-contiguous row stores (kills write amplification).
// CSR build (8x-replicated hist/scan/scatter) and spmm unchanged.

#define N_NODES 50000
#define N_EDGES 800000
#define KDIM 256
#define BK 32
#define REP 8
#define NC (N_NODES * REP)            // 400000 replicated counters
#define NB2 ((NC + 1023) / 1024)      // 391 scan blocks
#define NC_PAD (NB2 * 1024)           // 400384

typedef __attribute__((ext_vector_type(8))) short short8;
typedef __attribute__((ext_vector_type(4))) float f32x4;

__device__ __forceinline__ ushort f2bf(float f) {
    union { float f; unsigned u; } x; x.f = f;
    unsigned r = x.u + 0x7fffu + ((x.u >> 16) & 1u);  // RTN-even
    return (ushort)(r >> 16);
}
__device__ __forceinline__ float bf2f(ushort u) {
    union { unsigned u; float f; } x; x.u = ((unsigned)u) << 16;
    return x.f;
}

// async global->LDS, 16B per lane. LDS dest must be wave-uniform base
// (HW adds lane*16); global src is per-lane.
__device__ __forceinline__ void gld_lds16(const void* g, void* l) {
    __builtin_amdgcn_global_load_lds(
        (const __attribute__((address_space(1))) void*)g,
        (__attribute__((address_space(3))) void*)l, 16, 0, 0);
}

// ---------------- merged weight transpose-casts ----------------
// Wt[n*256 + k] = bf16(W[k*N + n]) for W1(256x256), W2(256x256), W3(256x128)
__global__ __launch_bounds__(256) void transpose_all_kernel(
        const float* __restrict__ W1, const float* __restrict__ W2,
        const float* __restrict__ W3, ushort* __restrict__ Wt1,
        ushort* __restrict__ Wt2, ushort* __restrict__ Wt3) {
    int id = blockIdx.x * blockDim.x + threadIdx.x;
    if (id < 65536) {
        int n = id >> 8, k = id & 255;
        Wt1[n * 256 + k] = f2bf(W1[k * 256 + n]);
    } else if (id < 131072) {
        int i = id - 65536, n = i >> 8, k = i & 255;
        Wt2[n * 256 + k] = f2bf(W2[k * 256 + n]);
    } else if (id < 163840) {
        int i = id - 131072, n = i >> 8, k = i & 255;
        Wt3[n * 256 + k] = f2bf(W3[k * 128 + n]);
    }
}

// ---------------- GEMM body: C[M,N] = A[M,256] @ Wt[N,256]^T, bf16 out ------
// 128x128 tile, 256 threads = 4 waves (2x2 of 64x64), 16x16x32 MFMA.
//
// Frag-major LDS granules (16B): slot S = (f*64 + lane) where f = half*4+sub,
// content = src[(base + (f>>2)*64 + (f&3)*16 + (lane&15)) * 256
//               + k0 + (lane>>4)*8 (+ h*4 for fp32 high half)].
// Fragment read for (sub, wave-half) = ds_read_b128 at slot contiguous in
// lane -> 0 bank conflicts (verified in R4). Staged with global_load_lds:
// LDS linear, global address carries the permutation.

template <bool AFP32>
__device__ __forceinline__ void gemm_body(
        const void* __restrict__ Ain, const ushort* __restrict__ Wt,
        ushort* __restrict__ C, int M, int N, int bx, int by) {
    // AFP32: A fp32 dbuf 2x16KB @0, B dbuf 2x8KB @32KB  -> 48KB
    // else : A bf16 dbuf 2x8KB  @0, B dbuf 2x8KB @16KB  -> 32KB
    __shared__ char smem[AFP32 ? 49152 : 32768];
    const int ABYTES = AFP32 ? 16384 : 8192;

    int t = threadIdx.x;
    int lane = t & 63;
    int w = t >> 6;
    int wbase = w * 64;                 // wave-uniform granule base within 256
    int row0 = bx * 128, col0 = by * 128;
    int wm2 = w & 1, wn2 = w >> 1;
    int wm = wm2 * 64, wn = wn2 * 64;
    int q = lane >> 4, mi = lane & 15;

    char* Ab0 = smem;
    char* Ab1 = smem + ABYTES;
    char* Bb0 = smem + 2 * ABYTES;
    char* Bb1 = smem + 2 * ABYTES + 8192;

    const float*  Af = (const float*)Ain;
    const ushort* Au = (const ushort*)Ain;

    auto stageA = [&](char* dst, int k0) {
        if (AFP32) {
            #pragma unroll
            for (int i = 0; i < 4; i++) {
                int D = i * 256 + t;            // granule 0..1023
                int h = D >> 9, s = D & 511;
                int f = s >> 6, lp = s & 63;
                int row = row0 + (f >> 2) * 64 + (f & 3) * 16 + (lp & 15);
                if (row >= M) row = M - 1;
                const float* g = Af + (size_t)row * KDIM + k0 + (lp >> 4) * 8 + h * 4;
                gld_lds16(g, dst + (i * 256 + wbase) * 16);
            }
        } else {
            #pragma unroll
            for (int i = 0; i < 2; i++) {
                int D = i * 256 + t;            // granule 0..511
                int f = D >> 6, lp = D & 63;
                int row = row0 + (f >> 2) * 64 + (f & 3) * 16 + (lp & 15);
                if (row >= M) row = M - 1;
                const ushort* g = Au + (size_t)row * KDIM + k0 + (lp >> 4) * 8;
                gld_lds16(g, dst + (i * 256 + wbase) * 16);
            }
        }
    };
    auto stageB = [&](char* dst, int k0) {
        #pragma unroll
        for (int i = 0; i < 2; i++) {
            int D = i * 256 + t;                // granule 0..511
            int f = D >> 6, lp = D & 63;
            int col = col0 + (f >> 2) * 64 + (f & 3) * 16 + (lp & 15);
            const ushort* g = Wt + (size_t)col * KDIM + k0 + (lp >> 4) * 8;
            gld_lds16(g, dst + (i * 256 + wbase) * 16);
        }
    };

    f32x4 acc[4][4];
    #pragma unroll
    for (int i = 0; i < 4; i++)
        #pragma unroll
        for (int j = 0; j < 4; j++) acc[i][j] = (f32x4)0.f;

    stageA(Ab0, 0);
    stageB(Bb0, 0);
    __syncthreads();   // drains vmcnt(0): buf0 ready

    #pragma unroll
    for (int kt = 0; kt < 8; kt++) {
        char* Acur = (kt & 1) ? Ab1 : Ab0;
        char* Bcur = (kt & 1) ? Bb1 : Bb0;
        // issue next tile's loads first: they fly under ds_read + MFMA
        if (kt < 7) {
            stageA((kt & 1) ? Ab0 : Ab1, (kt + 1) * BK);
            stageB((kt & 1) ? Bb0 : Bb1, (kt + 1) * BK);
        }

        short8 af[4], bfr[4];
        if (AFP32) {
            const float* As = (const float*)Acur;
            #pragma unroll
            for (int mt = 0; mt < 4; mt++) {
                int gA = (wm2 * 4 + mt) * 64 + lane;
                f32x4 lo = *(const f32x4*)(As + gA * 4);          // h=0 region
                f32x4 hi = *(const f32x4*)(As + 2048 + gA * 4);   // h=1 region
                af[mt][0] = (short)f2bf(lo[0]); af[mt][1] = (short)f2bf(lo[1]);
                af[mt][2] = (short)f2bf(lo[2]); af[mt][3] = (short)f2bf(lo[3]);
                af[mt][4] = (short)f2bf(hi[0]); af[mt][5] = (short)f2bf(hi[1]);
                af[mt][6] = (short)f2bf(hi[2]); af[mt][7] = (short)f2bf(hi[3]);
            }
        } else {
            #pragma unroll
            for (int mt = 0; mt < 4; mt++)
                af[mt] = *(const short8*)(Acur + ((wm2 * 4 + mt) * 64 + lane) * 16);
        }
        #pragma unroll
        for (int nt = 0; nt < 4; nt++)
            bfr[nt] = *(const short8*)(Bcur + ((wn2 * 4 + nt) * 64 + lane) * 16);

        #pragma unroll
        for (int mt = 0; mt < 4; mt++)
            #pragma unroll
            for (int nt = 0; nt < 4; nt++)
                acc[mt][nt] = __builtin_amdgcn_mfma_f32_16x16x32_bf16(
                    af[mt], bfr[nt], acc[mt][nt], 0, 0, 0);

        // one barrier per K-step: drains next-tile loads (vmcnt) and
        // guarantees all waves' ds_reads of Acur/Bcur are done before the
        // following iteration's staging overwrites them.
        __syncthreads();
    }

    // ---- epilogue: stage C tile in LDS, emit 256B-contiguous row stores ----
    ushort* Cs = (ushort*)smem;   // 128x128 bf16 = 32KB (fits both configs)
    #pragma unroll
    for (int mt = 0; mt < 4; mt++)
        #pragma unroll
        for (int r = 0; r < 4; r++)
            #pragma unroll
            for (int nt = 0; nt < 4; nt++)
                Cs[(wm + mt * 16 + q * 4 + r) * 128 + wn + nt * 16 + mi] =
                    f2bf(acc[mt][nt][r]);
    __syncthreads();
    #pragma unroll
    for (int i = 0; i < 8; i++) {
        int idx = i * 256 + t;          // 2048 granules of 16B
        int rr = idx >> 4, gc = idx & 15;
        int grow = row0 + rr;
        if (grow < M)
            *(short8*)&C[(size_t)grow * N + col0 + gc * 8] =
                *(const short8*)&Cs[rr * 128 + gc * 8];
    }
}

// layer-1 gemm (fp32 A, fused cast) + hist in one fat kernel.
// blocks [0, GB1): gemm tiles; blocks [GB1, GB1+3125): hist.
#define GB1 782   // 391 row-tiles x 2 col-tiles

__global__ __launch_bounds__(256) void gemm1_hist_kernel(
        const float* __restrict__ x, const ushort* __restrict__ Wt1,
        ushort* __restrict__ C, const int* __restrict__ rows,
        int* __restrict__ counts) {
    int b = blockIdx.x;
    if (b < GB1) {
        gemm_body<true>(x, Wt1, C, N_NODES, 256, b % 391, b / 391);
    } else {
        int e = (b - GB1) * 256 + threadIdx.x;
        if (e < N_EDGES) {
            int r = rows[e];
            atomicAdd(&counts[(r << 3) | (e & 7)], 1);
        }
    }
}

template <bool AFP32>
__global__ __launch_bounds__(256) void gemm_bf16_kernel(
        const void* __restrict__ Ain, const ushort* __restrict__ Wt,
        ushort* __restrict__ C, int M, int N) {
    gemm_body<AFP32>(Ain, Wt, C, M, N, blockIdx.x, blockIdx.y);
}

// ---------------- hierarchical scan over NC replicated counters ------------

__global__ __launch_bounds__(256) void scan_sums(const int* __restrict__ counts,
                                                 int* __restrict__ bsum) {
    __shared__ int ws[4];
    int b = blockIdx.x, t = threadIdx.x, lane = t & 63, wv = t >> 6;
    int4 v = *(const int4*)&counts[b * 1024 + t * 4];
    int s = v.x + v.y + v.z + v.w;
    #pragma unroll
    for (int off = 32; off >= 1; off >>= 1) s += __shfl_down(s, off, 64);
    if (lane == 0) ws[wv] = s;
    __syncthreads();
    if (t == 0) bsum[b] = ws[0] + ws[1] + ws[2] + ws[3];
}

// single block, 512 threads: exclusive scan of NB2 block sums; writes total.
__global__ __launch_bounds__(512) void scan_block(const int* __restrict__ bsum,
                                                  int* __restrict__ boff,
                                                  int* __restrict__ rp8, int nb) {
    __shared__ int ws[8];
    int t = threadIdx.x, lane = t & 63, wv = t >> 6;
    int v = (t < nb) ? bsum[t] : 0;
    int incl = v;
    #pragma unroll
    for (int off = 1; off < 64; off <<= 1) {
        int u = __shfl_up(incl, off, 64);
        if (lane >= off) incl += u;
    }
    if (lane == 63) ws[wv] = incl;
    __syncthreads();
    int wo = 0;
    #pragma unroll
    for (int j = 0; j < 7; j++) wo += (j < wv) ? ws[j] : 0;
    if (t < nb) boff[t] = wo + incl - v;
    if (t == 511) rp8[NC] = wo + incl;   // == N_EDGES
}

__global__ __launch_bounds__(256) void scan_apply(int* __restrict__ counts,
                                                  const int* __restrict__ boff,
                                                  int* __restrict__ rp8) {
    __shared__ int ws[4];
    int b = blockIdx.x, t = threadIdx.x, lane = t & 63, wv = t >> 6;
    int i = b * 1024 + t * 4;
    int4 v = *(const int4*)&counts[i];
    int s0 = v.x, s01 = s0 + v.y, s012 = s01 + v.z, tsum = s012 + v.w;
    int incl = tsum;
    #pragma unroll
    for (int off = 1; off < 64; off <<= 1) {
        int u = __shfl_up(incl, off, 64);
        if (lane >= off) incl += u;
    }
    if (lane == 63) ws[wv] = incl;
    __syncthreads();
    int woff = 0;
    #pragma unroll
    for (int j = 0; j < 3; j++) woff += (j < wv) ? ws[j] : 0;
    int base = boff[b] + woff + incl - tsum;
    if (i < NC)     rp8[i]     = base;
    if (i + 1 < NC) rp8[i + 1] = base + s0;
    if (i + 2 < NC) rp8[i + 2] = base + s01;
    if (i + 3 < NC) rp8[i + 3] = base + s012;
    *(int4*)&counts[i] = make_int4(0, 0, 0, 0);
}

__global__ void scatter_kernel(const int* __restrict__ rows, const int* __restrict__ cols,
                               const float* __restrict__ vals, const int* __restrict__ rp8,
                               int* __restrict__ counts, int2* __restrict__ cv) {
    int e = blockIdx.x * blockDim.x + threadIdx.x;
    if (e < N_EDGES) {
        int idx = (rows[e] << 3) | (e & 7);
        int pos = rp8[idx] + atomicAdd(&counts[idx], 1);
        cv[pos] = make_int2(cols[e], __float_as_int(vals[e]));
    }
}

// ---------------- SpMM (CSR): wave per row, EP edge-groups x 4 unroll ------

template <int F, bool RELU, bool OUT_BF16>
__global__ __launch_bounds__(256) void spmm_kernel(
        const ushort* __restrict__ H, const int* __restrict__ rp8,
        const int2* __restrict__ cv, const float* __restrict__ bias,
        void* __restrict__ out, int nrows) {
    constexpr int FL = F / 8;       // 32 (F=256) / 16 (F=128)
    constexpr int EP = 64 / FL;     // 2 / 4
    constexpr int STEP = EP * 4;    // 8 / 16 edges per iteration
    int wave = threadIdx.x >> 6, lane = threadIdx.x & 63;
    int r = blockIdx.x * 4 + wave;
    if (r >= nrows) return;
    int fl = lane % FL, ep = lane / FL;
    const ushort* Hl = H + fl * 8;

    float acc[8];
    #pragma unroll
    for (int j = 0; j < 8; j++) acc[j] = 0.f;

    int start = rp8[r * REP], end = rp8[r * REP + REP];
    for (int base = start; base < end; base += STEP) {
        int e0 = base + ep * 4;
        int2 m0 = cv[e0], m1 = cv[e0 + 1], m2 = cv[e0 + 2], m3 = cv[e0 + 3];
        int   c0 = (e0     < end) ? m0.x : 0;
        int   c1 = (e0 + 1 < end) ? m1.x : 0;
        int   c2 = (e0 + 2 < end) ? m2.x : 0;
        int   c3 = (e0 + 3 < end) ? m3.x : 0;
        float v0 = (e0     < end) ? __int_as_float(m0.y) : 0.f;
        float v1 = (e0 + 1 < end) ? __int_as_float(m1.y) : 0.f;
        float v2 = (e0 + 2 < end) ? __int_as_float(m2.y) : 0.f;
        float v3 = (e0 + 3 < end) ? __int_as_float(m3.y) : 0.f;
        short8 h0 = *(const short8*)&Hl[(size_t)c0 * F];
        short8 h1 = *(const short8*)&Hl[(size_t)c1 * F];
        short8 h2 = *(const short8*)&Hl[(size_t)c2 * F];
        short8 h3 = *(const short8*)&Hl[(size_t)c3 * F];
        #pragma unroll
        for (int j = 0; j < 8; j++)
            acc[j] += v0 * bf2f((ushort)h0[j]) + v1 * bf2f((ushort)h1[j])
                    + v2 * bf2f((ushort)h2[j]) + v3 * bf2f((ushort)h3[j]);
    }

    #pragma unroll
    for (int off = FL; off < 64; off <<= 1)
        #pragma unroll
        for (int j = 0; j < 8; j++) acc[j] += __shfl_down(acc[j], off, 64);

    if (ep == 0) {
        #pragma unroll
        for (int j = 0; j < 8; j++) {
            float o = acc[j] + bias[fl * 8 + j];
            if (RELU) o = fmaxf(o, 0.f);
            acc[j] = o;
        }
        if (OUT_BF16) {
            short8 ob;
            #pragma unroll
            for (int j = 0; j < 8; j++) ob[j] = (short)f2bf(acc[j]);
            *(short8*)((ushort*)out + (size_t)r * F + fl * 8) = ob;
        } else {
            float* of = (float*)out + (size_t)r * F + fl * 8;
            *(float4*)&of[0] = make_float4(acc[0], acc[1], acc[2], acc[3]);
            *(float4*)&of[4] = make_float4(acc[4], acc[5], acc[6], acc[7]);
        }
    }
}

// ---------------- launch ----------------

extern "C" void kernel_launch(void* const* d_in, const int* in_sizes, int n_in,
                              void* d_out, int out_size, void* d_ws, size_t ws_size,
                              hipStream_t stream) {
    const float* x    = (const float*)d_in[0];
    const float* av   = (const float*)d_in[1];
    const int*   rows = (const int*)d_in[2];
    const int*   cols = (const int*)d_in[3];
    const float* W1   = (const float*)d_in[4];
    const float* b1   = (const float*)d_in[5];
    const float* W2   = (const float*)d_in[6];
    const float* b2   = (const float*)d_in[7];
    const float* W3   = (const float*)d_in[8];
    const float* b3   = (const float*)d_in[9];
    float* out = (float*)d_out;

    const int N = N_NODES, E = N_EDGES;

    char* p = (char*)d_ws;
    auto carve = [&](size_t bytes) {
        void* q = (void*)p;
        p += (bytes + 255) & ~(size_t)255;
        return q;
    };
    ushort* bufG = (ushort*)carve((size_t)N * 256 * 2);
    ushort* bufH = (ushort*)carve((size_t)N * 256 * 2);
    ushort* Wt1  = (ushort*)carve((size_t)256 * 256 * 2);
    ushort* Wt2  = (ushort*)carve((size_t)256 * 256 * 2);
    ushort* Wt3  = (ushort*)carve((size_t)128 * 256 * 2);
    int*    rp8    = (int*)carve((size_t)(NC + 1) * 4);
    int*    counts = (int*)carve((size_t)NC_PAD * 4);
    int*    bsum   = (int*)carve((size_t)NB2 * 4);
    int*    boff   = (int*)carve((size_t)NB2 * 4);
    int2*   cv     = (int2*)carve((size_t)(E + 16) * 8);

    hipMemsetAsync(counts, 0, (size_t)NC_PAD * 4, stream);
    transpose_all_kernel<<<(163840 + 255) / 256, 256, 0, stream>>>(W1, W2, W3, Wt1, Wt2, Wt3);

    // layer-1 gemm (pipelined) overlapped with hist (latency-bound)
    gemm1_hist_kernel<<<GB1 + (E + 255) / 256, 256, 0, stream>>>(x, Wt1, bufG, rows, counts);

    scan_sums<<<NB2, 256, 0, stream>>>(counts, bsum);
    scan_block<<<1, 512, 0, stream>>>(bsum, boff, rp8, NB2);
    scan_apply<<<NB2, 256, 0, stream>>>(counts, boff, rp8);
    scatter_kernel<<<(E + 255) / 256, 256, 0, stream>>>(rows, cols, av, rp8, counts, cv);

    int spmm_blocks = (N + 3) / 4;
    spmm_kernel<256, true, true><<<spmm_blocks, 256, 0, stream>>>(bufG, rp8, cv, b1, bufH, N);
    gemm_bf16_kernel<false><<<dim3(391, 2), 256, 0, stream>>>(bufH, Wt2, bufG, N, 256);
    spmm_kernel<256, true, true><<<spmm_blocks, 256, 0, stream>>>(bufG, rp8, cv, b2, bufH, N);
    gemm_bf16_kernel<false><<<dim3(391, 1), 256, 0, stream>>>(bufH, Wt3, bufG, N, 128);
    spmm_kernel<128, false, false><<<spmm_blocks, 256, 0, stream>>>(bufG, rp8, cv, b3, out, N);
}

// Round 3
// 362.672 us; speedup vs baseline: 1.0889x; 1.0253x over previous
//
#include <hip/hip_runtime.h>
#include <hip/hip_bf16.h>

// GCN R6: single-pass ELL CSR build (one atomicAdd per edge, capacity-64
// rows) replaces hist+scan+scatter (halves atomic count, deletes 4
// dispatches). ELL build fused into gemm1 fat kernel. GEMM bodies = R5
// (global_load_lds pipelined, frag-major LDS). spmm reads cnt[] + r<<6.

#define N_NODES 50000
#define N_EDGES 800000
#define KDIM 256
#define BK 32
#define ELLCAP 64            // max degree: Poisson(16) tail ~ e^-125, safe
#define ELLB 782             // ell-build blocks: 782*256*4 >= 800000 edges

typedef __attribute__((ext_vector_type(8))) short short8;
typedef __attribute__((ext_vector_type(4))) float f32x4;

__device__ __forceinline__ ushort f2bf(float f) {
    union { float f; unsigned u; } x; x.f = f;
    unsigned r = x.u + 0x7fffu + ((x.u >> 16) & 1u);  // RTN-even
    return (ushort)(r >> 16);
}
__device__ __forceinline__ float bf2f(ushort u) {
    union { unsigned u; float f; } x; x.u = ((unsigned)u) << 16;
    return x.f;
}

// async global->LDS, 16B per lane. LDS dest must be wave-uniform base
// (HW adds lane*16); global src is per-lane.
__device__ __forceinline__ void gld_lds16(const void* g, void* l) {
    __builtin_amdgcn_global_load_lds(
        (const __attribute__((address_space(1))) void*)g,
        (__attribute__((address_space(3))) void*)l, 16, 0, 0);
}

// ---------------- merged weight transpose-casts ----------------
// Wt[n*256 + k] = bf16(W[k*N + n]) for W1(256x256), W2(256x256), W3(256x128)
__global__ __launch_bounds__(256) void transpose_all_kernel(
        const float* __restrict__ W1, const float* __restrict__ W2,
        const float* __restrict__ W3, ushort* __restrict__ Wt1,
        ushort* __restrict__ Wt2, ushort* __restrict__ Wt3) {
    int id = blockIdx.x * blockDim.x + threadIdx.x;
    if (id < 65536) {
        int n = id >> 8, k = id & 255;
        Wt1[n * 256 + k] = f2bf(W1[k * 256 + n]);
    } else if (id < 131072) {
        int i = id - 65536, n = i >> 8, k = i & 255;
        Wt2[n * 256 + k] = f2bf(W2[k * 256 + n]);
    } else if (id < 163840) {
        int i = id - 131072, n = i >> 8, k = i & 255;
        Wt3[n * 256 + k] = f2bf(W3[k * 128 + n]);
    }
}

// ---------------- GEMM body: C[M,N] = A[M,256] @ Wt[N,256]^T, bf16 out ------
// 128x128 tile, 256 threads = 4 waves (2x2 of 64x64), 16x16x32 MFMA.
// Frag-major LDS granules (16B) staged via global_load_lds with the
// permutation carried by the per-lane global source address; LDS linear.
// One barrier per K-step; next tile's loads fly under ds_read+MFMA.

template <bool AFP32>
__device__ __forceinline__ void gemm_body(
        const void* __restrict__ Ain, const ushort* __restrict__ Wt,
        ushort* __restrict__ C, int M, int N, int bx, int by) {
    // AFP32: A fp32 dbuf 2x16KB @0, B dbuf 2x8KB @32KB  -> 48KB
    // else : A bf16 dbuf 2x8KB  @0, B dbuf 2x8KB @16KB  -> 32KB
    __shared__ char smem[AFP32 ? 49152 : 32768];
    const int ABYTES = AFP32 ? 16384 : 8192;

    int t = threadIdx.x;
    int lane = t & 63;
    int w = t >> 6;
    int wbase = w * 64;                 // wave-uniform granule base within 256
    int row0 = bx * 128, col0 = by * 128;
    int wm2 = w & 1, wn2 = w >> 1;
    int wm = wm2 * 64, wn = wn2 * 64;
    int q = lane >> 4, mi = lane & 15;

    char* Ab0 = smem;
    char* Ab1 = smem + ABYTES;
    char* Bb0 = smem + 2 * ABYTES;
    char* Bb1 = smem + 2 * ABYTES + 8192;

    const float*  Af = (const float*)Ain;
    const ushort* Au = (const ushort*)Ain;

    auto stageA = [&](char* dst, int k0) {
        if (AFP32) {
            #pragma unroll
            for (int i = 0; i < 4; i++) {
                int D = i * 256 + t;            // granule 0..1023
                int h = D >> 9, s = D & 511;
                int f = s >> 6, lp = s & 63;
                int row = row0 + (f >> 2) * 64 + (f & 3) * 16 + (lp & 15);
                if (row >= M) row = M - 1;
                const float* g = Af + (size_t)row * KDIM + k0 + (lp >> 4) * 8 + h * 4;
                gld_lds16(g, dst + (i * 256 + wbase) * 16);
            }
        } else {
            #pragma unroll
            for (int i = 0; i < 2; i++) {
                int D = i * 256 + t;            // granule 0..511
                int f = D >> 6, lp = D & 63;
                int row = row0 + (f >> 2) * 64 + (f & 3) * 16 + (lp & 15);
                if (row >= M) row = M - 1;
                const ushort* g = Au + (size_t)row * KDIM + k0 + (lp >> 4) * 8;
                gld_lds16(g, dst + (i * 256 + wbase) * 16);
            }
        }
    };
    auto stageB = [&](char* dst, int k0) {
        #pragma unroll
        for (int i = 0; i < 2; i++) {
            int D = i * 256 + t;                // granule 0..511
            int f = D >> 6, lp = D & 63;
            int col = col0 + (f >> 2) * 64 + (f & 3) * 16 + (lp & 15);
            const ushort* g = Wt + (size_t)col * KDIM + k0 + (lp >> 4) * 8;
            gld_lds16(g, dst + (i * 256 + wbase) * 16);
        }
    };

    f32x4 acc[4][4];
    #pragma unroll
    for (int i = 0; i < 4; i++)
        #pragma unroll
        for (int j = 0; j < 4; j++) acc[i][j] = (f32x4)0.f;

    stageA(Ab0, 0);
    stageB(Bb0, 0);
    __syncthreads();   // drains vmcnt(0): buf0 ready

    #pragma unroll
    for (int kt = 0; kt < 8; kt++) {
        char* Acur = (kt & 1) ? Ab1 : Ab0;
        char* Bcur = (kt & 1) ? Bb1 : Bb0;
        // issue next tile's loads first: they fly under ds_read + MFMA
        if (kt < 7) {
            stageA((kt & 1) ? Ab0 : Ab1, (kt + 1) * BK);
            stageB((kt & 1) ? Bb0 : Bb1, (kt + 1) * BK);
        }

        short8 af[4], bfr[4];
        if (AFP32) {
            const float* As = (const float*)Acur;
            #pragma unroll
            for (int mt = 0; mt < 4; mt++) {
                int gA = (wm2 * 4 + mt) * 64 + lane;
                f32x4 lo = *(const f32x4*)(As + gA * 4);          // h=0 region
                f32x4 hi = *(const f32x4*)(As + 2048 + gA * 4);   // h=1 region
                af[mt][0] = (short)f2bf(lo[0]); af[mt][1] = (short)f2bf(lo[1]);
                af[mt][2] = (short)f2bf(lo[2]); af[mt][3] = (short)f2bf(lo[3]);
                af[mt][4] = (short)f2bf(hi[0]); af[mt][5] = (short)f2bf(hi[1]);
                af[mt][6] = (short)f2bf(hi[2]); af[mt][7] = (short)f2bf(hi[3]);
            }
        } else {
            #pragma unroll
            for (int mt = 0; mt < 4; mt++)
                af[mt] = *(const short8*)(Acur + ((wm2 * 4 + mt) * 64 + lane) * 16);
        }
        #pragma unroll
        for (int nt = 0; nt < 4; nt++)
            bfr[nt] = *(const short8*)(Bcur + ((wn2 * 4 + nt) * 64 + lane) * 16);

        #pragma unroll
        for (int mt = 0; mt < 4; mt++)
            #pragma unroll
            for (int nt = 0; nt < 4; nt++)
                acc[mt][nt] = __builtin_amdgcn_mfma_f32_16x16x32_bf16(
                    af[mt], bfr[nt], acc[mt][nt], 0, 0, 0);

        __syncthreads();
    }

    // ---- epilogue: stage C tile in LDS, emit 256B-contiguous row stores ----
    ushort* Cs = (ushort*)smem;   // 128x128 bf16 = 32KB (fits both configs)
    #pragma unroll
    for (int mt = 0; mt < 4; mt++)
        #pragma unroll
        for (int r = 0; r < 4; r++)
            #pragma unroll
            for (int nt = 0; nt < 4; nt++)
                Cs[(wm + mt * 16 + q * 4 + r) * 128 + wn + nt * 16 + mi] =
                    f2bf(acc[mt][nt][r]);
    __syncthreads();
    #pragma unroll
    for (int i = 0; i < 8; i++) {
        int idx = i * 256 + t;          // 2048 granules of 16B
        int rr = idx >> 4, gc = idx & 15;
        int grow = row0 + rr;
        if (grow < M)
            *(short8*)&C[(size_t)grow * N + col0 + gc * 8] =
                *(const short8*)&Cs[rr * 128 + gc * 8];
    }
}

// ---------------- ELL build (4 edges/thread) fused with layer-1 gemm -------
// blocks [0, ELLB): ell build; blocks [ELLB, ELLB+782): gemm tiles.

__global__ __launch_bounds__(256) void gemm1_ell_kernel(
        const float* __restrict__ x, const ushort* __restrict__ Wt1,
        ushort* __restrict__ C, const int* __restrict__ rows,
        const int* __restrict__ cols, const float* __restrict__ vals,
        int* __restrict__ cnt, int2* __restrict__ cv) {
    int b = blockIdx.x;
    if (b < ELLB) {
        int e0 = (b * 256 + threadIdx.x) * 4;
        if (e0 < N_EDGES) {           // N_EDGES % 4 == 0: full quad or skip
            int4   r4 = *(const int4*)&rows[e0];
            int4   c4 = *(const int4*)&cols[e0];
            float4 v4 = *(const float4*)&vals[e0];
            int p0 = atomicAdd(&cnt[r4.x], 1);
            cv[(r4.x << 6) + p0] = make_int2(c4.x, __float_as_int(v4.x));
            int p1 = atomicAdd(&cnt[r4.y], 1);
            cv[(r4.y << 6) + p1] = make_int2(c4.y, __float_as_int(v4.y));
            int p2 = atomicAdd(&cnt[r4.z], 1);
            cv[(r4.z << 6) + p2] = make_int2(c4.z, __float_as_int(v4.z));
            int p3 = atomicAdd(&cnt[r4.w], 1);
            cv[(r4.w << 6) + p3] = make_int2(c4.w, __float_as_int(v4.w));
        }
    } else {
        int g = b - ELLB;
        gemm_body<true>(x, Wt1, C, N_NODES, 256, g % 391, g / 391);
    }
}

template <bool AFP32>
__global__ __launch_bounds__(256) void gemm_bf16_kernel(
        const void* __restrict__ Ain, const ushort* __restrict__ Wt,
        ushort* __restrict__ C, int M, int N) {
    gemm_body<AFP32>(Ain, Wt, C, M, N, blockIdx.x, blockIdx.y);
}

// ---------------- SpMM (ELL): wave per row, EP edge-groups x 4 unroll ------
// Row r's edges live at cv[r*64 .. r*64+cnt[r]). Guards clamp cols of
// slots past nnz to 0 (their cv contents are uninitialized but never used).

template <int F, bool RELU, bool OUT_BF16>
__global__ __launch_bounds__(256) void spmm_kernel(
        const ushort* __restrict__ H, const int* __restrict__ cnt,
        const int2* __restrict__ cv, const float* __restrict__ bias,
        void* __restrict__ out, int nrows) {
    constexpr int FL = F / 8;       // 32 (F=256) / 16 (F=128)
    constexpr int EP = 64 / FL;     // 2 / 4
    constexpr int STEP = EP * 4;    // 8 / 16 edges per iteration
    int wave = threadIdx.x >> 6, lane = threadIdx.x & 63;
    int r = blockIdx.x * 4 + wave;
    if (r >= nrows) return;
    int fl = lane % FL, ep = lane / FL;
    const ushort* Hl = H + fl * 8;

    float acc[8];
    #pragma unroll
    for (int j = 0; j < 8; j++) acc[j] = 0.f;

    int start = r << 6;             // ELLCAP = 64
    int end = start + cnt[r];
    for (int base = start; base < end; base += STEP) {
        int e0 = base + ep * 4;
        int2 m0 = cv[e0], m1 = cv[e0 + 1], m2 = cv[e0 + 2], m3 = cv[e0 + 3];
        int   c0 = (e0     < end) ? m0.x : 0;
        int   c1 = (e0 + 1 < end) ? m1.x : 0;
        int   c2 = (e0 + 2 < end) ? m2.x : 0;
        int   c3 = (e0 + 3 < end) ? m3.x : 0;
        float v0 = (e0     < end) ? __int_as_float(m0.y) : 0.f;
        float v1 = (e0 + 1 < end) ? __int_as_float(m1.y) : 0.f;
        float v2 = (e0 + 2 < end) ? __int_as_float(m2.y) : 0.f;
        float v3 = (e0 + 3 < end) ? __int_as_float(m3.y) : 0.f;
        short8 h0 = *(const short8*)&Hl[(size_t)c0 * F];
        short8 h1 = *(const short8*)&Hl[(size_t)c1 * F];
        short8 h2 = *(const short8*)&Hl[(size_t)c2 * F];
        short8 h3 = *(const short8*)&Hl[(size_t)c3 * F];
        #pragma unroll
        for (int j = 0; j < 8; j++)
            acc[j] += v0 * bf2f((ushort)h0[j]) + v1 * bf2f((ushort)h1[j])
                    + v2 * bf2f((ushort)h2[j]) + v3 * bf2f((ushort)h3[j]);
    }

    #pragma unroll
    for (int off = FL; off < 64; off <<= 1)
        #pragma unroll
        for (int j = 0; j < 8; j++) acc[j] += __shfl_down(acc[j], off, 64);

    if (ep == 0) {
        #pragma unroll
        for (int j = 0; j < 8; j++) {
            float o = acc[j] + bias[fl * 8 + j];
            if (RELU) o = fmaxf(o, 0.f);
            acc[j] = o;
        }
        if (OUT_BF16) {
            short8 ob;
            #pragma unroll
            for (int j = 0; j < 8; j++) ob[j] = (short)f2bf(acc[j]);
            *(short8*)((ushort*)out + (size_t)r * F + fl * 8) = ob;
        } else {
            float* of = (float*)out + (size_t)r * F + fl * 8;
            *(float4*)&of[0] = make_float4(acc[0], acc[1], acc[2], acc[3]);
            *(float4*)&of[4] = make_float4(acc[4], acc[5], acc[6], acc[7]);
        }
    }
}

// ---------------- launch ----------------

extern "C" void kernel_launch(void* const* d_in, const int* in_sizes, int n_in,
                              void* d_out, int out_size, void* d_ws, size_t ws_size,
                              hipStream_t stream) {
    const float* x    = (const float*)d_in[0];
    const float* av   = (const float*)d_in[1];
    const int*   rows = (const int*)d_in[2];
    const int*   cols = (const int*)d_in[3];
    const float* W1   = (const float*)d_in[4];
    const float* b1   = (const float*)d_in[5];
    const float* W2   = (const float*)d_in[6];
    const float* b2   = (const float*)d_in[7];
    const float* W3   = (const float*)d_in[8];
    const float* b3   = (const float*)d_in[9];
    float* out = (float*)d_out;

    const int N = N_NODES;

    char* p = (char*)d_ws;
    auto carve = [&](size_t bytes) {
        void* q = (void*)p;
        p += (bytes + 255) & ~(size_t)255;
        return q;
    };
    ushort* bufG = (ushort*)carve((size_t)N * 256 * 2);
    ushort* bufH = (ushort*)carve((size_t)N * 256 * 2);
    ushort* Wt1  = (ushort*)carve((size_t)256 * 256 * 2);
    ushort* Wt2  = (ushort*)carve((size_t)256 * 256 * 2);
    ushort* Wt3  = (ushort*)carve((size_t)128 * 256 * 2);
    int*    cnt  = (int*)carve((size_t)N * 4);
    int2*   cv   = (int2*)carve((size_t)N * ELLCAP * 8);   // 25.6 MB

    hipMemsetAsync(cnt, 0, (size_t)N * 4, stream);
    transpose_all_kernel<<<(163840 + 255) / 256, 256, 0, stream>>>(W1, W2, W3, Wt1, Wt2, Wt3);

    // ELL build (atomic-throughput bound) overlapped with layer-1 gemm
    gemm1_ell_kernel<<<ELLB + 782, 256, 0, stream>>>(x, Wt1, bufG, rows, cols, av, cnt, cv);

    int spmm_blocks = (N + 3) / 4;
    spmm_kernel<256, true, true><<<spmm_blocks, 256, 0, stream>>>(bufG, cnt, cv, b1, bufH, N);
    gemm_bf16_kernel<false><<<dim3(391, 2), 256, 0, stream>>>(bufH, Wt2, bufG, N, 256);
    spmm_kernel<256, true, true><<<spmm_blocks, 256, 0, stream>>>(bufG, cnt, cv, b2, bufH, N);
    gemm_bf16_kernel<false><<<dim3(391, 1), 256, 0, stream>>>(bufH, Wt3, bufG, N, 128);
    spmm_kernel<128, false, false><<<spmm_blocks, 256, 0, stream>>>(bufG, cnt, cv, b3, out, N);
}

// Round 4
// 362.201 us; speedup vs baseline: 1.0903x; 1.0013x over previous
//
#include <hip/hip_runtime.h>
#include <hip/hip_bf16.h>

// GCN R7: (1) ELL build un-fused from gemm1 (LDS-free, fused with weight
// transpose instead -> full occupancy for the atomic/scatter phase; gemm1
// standalone at 3 blocks/CU). (2) SpMM pipeline deepened to 8 gathers in
// flight per lane (STEP=16/32), meta as int4 pairs; most rows finish in one
// gather round. (3) cv carve padded +128 entries (tail-row overread).

#define N_NODES 50000
#define N_EDGES 800000
#define KDIM 256
#define BK 32
#define ELLCAP 64            // max degree: Poisson(16) tail ~ e^-125, safe
#define ELLB 782             // ell-build blocks: 782*256*4 >= 800000 edges
#define TRB 640              // transpose blocks: 640*256 = 163840 ids

typedef __attribute__((ext_vector_type(8))) short short8;
typedef __attribute__((ext_vector_type(4))) float f32x4;

__device__ __forceinline__ ushort f2bf(float f) {
    union { float f; unsigned u; } x; x.f = f;
    unsigned r = x.u + 0x7fffu + ((x.u >> 16) & 1u);  // RTN-even
    return (ushort)(r >> 16);
}
__device__ __forceinline__ float bf2f(ushort u) {
    union { unsigned u; float f; } x; x.u = ((unsigned)u) << 16;
    return x.f;
}

// async global->LDS, 16B per lane. LDS dest must be wave-uniform base
// (HW adds lane*16); global src is per-lane.
__device__ __forceinline__ void gld_lds16(const void* g, void* l) {
    __builtin_amdgcn_global_load_lds(
        (const __attribute__((address_space(1))) void*)g,
        (__attribute__((address_space(3))) void*)l, 16, 0, 0);
}

// ---------------- fused weight transpose-casts + ELL build ----------------
// blocks [0, TRB): Wt[n*256+k] = bf16(W[k*N+n]) for W1/W2/W3.
// blocks [TRB, TRB+ELLB): 4 edges/thread, one atomicAdd each, scatter to
// cv[r*64+p]. No LDS anywhere -> full wave occupancy for the atomic phase.
__global__ __launch_bounds__(256) void transpose_ell_kernel(
        const float* __restrict__ W1, const float* __restrict__ W2,
        const float* __restrict__ W3, ushort* __restrict__ Wt1,
        ushort* __restrict__ Wt2, ushort* __restrict__ Wt3,
        const int* __restrict__ rows, const int* __restrict__ cols,
        const float* __restrict__ vals, int* __restrict__ cnt,
        int2* __restrict__ cv) {
    int b = blockIdx.x;
    if (b < TRB) {
        int id = b * 256 + threadIdx.x;
        if (id < 65536) {
            int n = id >> 8, k = id & 255;
            Wt1[n * 256 + k] = f2bf(W1[k * 256 + n]);
        } else if (id < 131072) {
            int i = id - 65536, n = i >> 8, k = i & 255;
            Wt2[n * 256 + k] = f2bf(W2[k * 256 + n]);
        } else {
            int i = id - 131072, n = i >> 8, k = i & 255;
            Wt3[n * 256 + k] = f2bf(W3[k * 128 + n]);
        }
    } else {
        int e0 = ((b - TRB) * 256 + threadIdx.x) * 4;
        if (e0 < N_EDGES) {           // N_EDGES % 4 == 0: full quad or skip
            int4   r4 = *(const int4*)&rows[e0];
            int4   c4 = *(const int4*)&cols[e0];
            float4 v4 = *(const float4*)&vals[e0];
            int p0 = atomicAdd(&cnt[r4.x], 1);
            cv[(r4.x << 6) + p0] = make_int2(c4.x, __float_as_int(v4.x));
            int p1 = atomicAdd(&cnt[r4.y], 1);
            cv[(r4.y << 6) + p1] = make_int2(c4.y, __float_as_int(v4.y));
            int p2 = atomicAdd(&cnt[r4.z], 1);
            cv[(r4.z << 6) + p2] = make_int2(c4.z, __float_as_int(v4.z));
            int p3 = atomicAdd(&cnt[r4.w], 1);
            cv[(r4.w << 6) + p3] = make_int2(c4.w, __float_as_int(v4.w));
        }
    }
}

// ---------------- GEMM body: C[M,N] = A[M,256] @ Wt[N,256]^T, bf16 out ------
// 128x128 tile, 256 threads = 4 waves (2x2 of 64x64), 16x16x32 MFMA.
// Frag-major LDS granules (16B) staged via global_load_lds with the
// permutation carried by the per-lane global source address; LDS linear.
// One barrier per K-step; next tile's loads fly under ds_read+MFMA.

template <bool AFP32>
__device__ __forceinline__ void gemm_body(
        const void* __restrict__ Ain, const ushort* __restrict__ Wt,
        ushort* __restrict__ C, int M, int N, int bx, int by) {
    // AFP32: A fp32 dbuf 2x16KB @0, B dbuf 2x8KB @32KB  -> 48KB
    // else : A bf16 dbuf 2x8KB  @0, B dbuf 2x8KB @16KB  -> 32KB
    __shared__ char smem[AFP32 ? 49152 : 32768];
    const int ABYTES = AFP32 ? 16384 : 8192;

    int t = threadIdx.x;
    int lane = t & 63;
    int w = t >> 6;
    int wbase = w * 64;                 // wave-uniform granule base within 256
    int row0 = bx * 128, col0 = by * 128;
    int wm2 = w & 1, wn2 = w >> 1;
    int wm = wm2 * 64, wn = wn2 * 64;
    int q = lane >> 4, mi = lane & 15;

    char* Ab0 = smem;
    char* Ab1 = smem + ABYTES;
    char* Bb0 = smem + 2 * ABYTES;
    char* Bb1 = smem + 2 * ABYTES + 8192;

    const float*  Af = (const float*)Ain;
    const ushort* Au = (const ushort*)Ain;

    auto stageA = [&](char* dst, int k0) {
        if (AFP32) {
            #pragma unroll
            for (int i = 0; i < 4; i++) {
                int D = i * 256 + t;            // granule 0..1023
                int h = D >> 9, s = D & 511;
                int f = s >> 6, lp = s & 63;
                int row = row0 + (f >> 2) * 64 + (f & 3) * 16 + (lp & 15);
                if (row >= M) row = M - 1;
                const float* g = Af + (size_t)row * KDIM + k0 + (lp >> 4) * 8 + h * 4;
                gld_lds16(g, dst + (i * 256 + wbase) * 16);
            }
        } else {
            #pragma unroll
            for (int i = 0; i < 2; i++) {
                int D = i * 256 + t;            // granule 0..511
                int f = D >> 6, lp = D & 63;
                int row = row0 + (f >> 2) * 64 + (f & 3) * 16 + (lp & 15);
                if (row >= M) row = M - 1;
                const ushort* g = Au + (size_t)row * KDIM + k0 + (lp >> 4) * 8;
                gld_lds16(g, dst + (i * 256 + wbase) * 16);
            }
        }
    };
    auto stageB = [&](char* dst, int k0) {
        #pragma unroll
        for (int i = 0; i < 2; i++) {
            int D = i * 256 + t;                // granule 0..511
            int f = D >> 6, lp = D & 63;
            int col = col0 + (f >> 2) * 64 + (f & 3) * 16 + (lp & 15);
            const ushort* g = Wt + (size_t)col * KDIM + k0 + (lp >> 4) * 8;
            gld_lds16(g, dst + (i * 256 + wbase) * 16);
        }
    };

    f32x4 acc[4][4];
    #pragma unroll
    for (int i = 0; i < 4; i++)
        #pragma unroll
        for (int j = 0; j < 4; j++) acc[i][j] = (f32x4)0.f;

    stageA(Ab0, 0);
    stageB(Bb0, 0);
    __syncthreads();   // drains vmcnt(0): buf0 ready

    #pragma unroll
    for (int kt = 0; kt < 8; kt++) {
        char* Acur = (kt & 1) ? Ab1 : Ab0;
        char* Bcur = (kt & 1) ? Bb1 : Bb0;
        // issue next tile's loads first: they fly under ds_read + MFMA
        if (kt < 7) {
            stageA((kt & 1) ? Ab0 : Ab1, (kt + 1) * BK);
            stageB((kt & 1) ? Bb0 : Bb1, (kt + 1) * BK);
        }

        short8 af[4], bfr[4];
        if (AFP32) {
            const float* As = (const float*)Acur;
            #pragma unroll
            for (int mt = 0; mt < 4; mt++) {
                int gA = (wm2 * 4 + mt) * 64 + lane;
                f32x4 lo = *(const f32x4*)(As + gA * 4);          // h=0 region
                f32x4 hi = *(const f32x4*)(As + 2048 + gA * 4);   // h=1 region
                af[mt][0] = (short)f2bf(lo[0]); af[mt][1] = (short)f2bf(lo[1]);
                af[mt][2] = (short)f2bf(lo[2]); af[mt][3] = (short)f2bf(lo[3]);
                af[mt][4] = (short)f2bf(hi[0]); af[mt][5] = (short)f2bf(hi[1]);
                af[mt][6] = (short)f2bf(hi[2]); af[mt][7] = (short)f2bf(hi[3]);
            }
        } else {
            #pragma unroll
            for (int mt = 0; mt < 4; mt++)
                af[mt] = *(const short8*)(Acur + ((wm2 * 4 + mt) * 64 + lane) * 16);
        }
        #pragma unroll
        for (int nt = 0; nt < 4; nt++)
            bfr[nt] = *(const short8*)(Bcur + ((wn2 * 4 + nt) * 64 + lane) * 16);

        #pragma unroll
        for (int mt = 0; mt < 4; mt++)
            #pragma unroll
            for (int nt = 0; nt < 4; nt++)
                acc[mt][nt] = __builtin_amdgcn_mfma_f32_16x16x32_bf16(
                    af[mt], bfr[nt], acc[mt][nt], 0, 0, 0);

        __syncthreads();
    }

    // ---- epilogue: stage C tile in LDS, emit 256B-contiguous row stores ----
    ushort* Cs = (ushort*)smem;   // 128x128 bf16 = 32KB (fits both configs)
    #pragma unroll
    for (int mt = 0; mt < 4; mt++)
        #pragma unroll
        for (int r = 0; r < 4; r++)
            #pragma unroll
            for (int nt = 0; nt < 4; nt++)
                Cs[(wm + mt * 16 + q * 4 + r) * 128 + wn + nt * 16 + mi] =
                    f2bf(acc[mt][nt][r]);
    __syncthreads();
    #pragma unroll
    for (int i = 0; i < 8; i++) {
        int idx = i * 256 + t;          // 2048 granules of 16B
        int rr = idx >> 4, gc = idx & 15;
        int grow = row0 + rr;
        if (grow < M)
            *(short8*)&C[(size_t)grow * N + col0 + gc * 8] =
                *(const short8*)&Cs[rr * 128 + gc * 8];
    }
}

template <bool AFP32>
__global__ __launch_bounds__(256) void gemm_bf16_kernel(
        const void* __restrict__ Ain, const ushort* __restrict__ Wt,
        ushort* __restrict__ C, int M, int N) {
    gemm_body<AFP32>(Ain, Wt, C, M, N, blockIdx.x, blockIdx.y);
}

// ---------------- SpMM (ELL): wave per row, EP groups x 8-deep gathers -----
// Row r's edges live at cv[r*64 .. r*64+cnt[r]). 8 gathers in flight per
// lane; guards zero vals/clamp cols for slots past nnz (those gathers hit
// H row 0, which stays L1-hot -> negligible). Meta loaded as int4 pairs.

template <int F, bool RELU, bool OUT_BF16>
__global__ __launch_bounds__(256) void spmm_kernel(
        const ushort* __restrict__ H, const int* __restrict__ cnt,
        const int2* __restrict__ cv, const float* __restrict__ bias,
        void* __restrict__ out, int nrows) {
    constexpr int FL = F / 8;       // 32 (F=256) / 16 (F=128)
    constexpr int EP = 64 / FL;     // 2 / 4
    constexpr int STEP = EP * 8;    // 16 / 32 edges per iteration
    int wave = threadIdx.x >> 6, lane = threadIdx.x & 63;
    int r = blockIdx.x * 4 + wave;
    if (r >= nrows) return;
    int fl = lane % FL, ep = lane / FL;
    const ushort* Hl = H + fl * 8;

    float acc[8];
    #pragma unroll
    for (int j = 0; j < 8; j++) acc[j] = 0.f;

    int start = r << 6;             // ELLCAP = 64
    int end = start + cnt[r];
    for (int base = start; base < end; base += STEP) {
        int e0 = base + ep * 8;     // 16B-aligned into cv
        int4 ma = *(const int4*)&cv[e0];
        int4 mb = *(const int4*)&cv[e0 + 2];
        int4 mc = *(const int4*)&cv[e0 + 4];
        int4 md = *(const int4*)&cv[e0 + 6];
        int   c[8];
        float v[8];
        c[0] = ma.x; v[0] = __int_as_float(ma.y);
        c[1] = ma.z; v[1] = __int_as_float(ma.w);
        c[2] = mb.x; v[2] = __int_as_float(mb.y);
        c[3] = mb.z; v[3] = __int_as_float(mb.w);
        c[4] = mc.x; v[4] = __int_as_float(mc.y);
        c[5] = mc.z; v[5] = __int_as_float(mc.w);
        c[6] = md.x; v[6] = __int_as_float(md.y);
        c[7] = md.z; v[7] = __int_as_float(md.w);
        #pragma unroll
        for (int u = 0; u < 8; u++) {
            if (e0 + u >= end) { c[u] = 0; v[u] = 0.f; }
        }
        short8 h[8];
        #pragma unroll
        for (int u = 0; u < 8; u++)
            h[u] = *(const short8*)&Hl[(size_t)c[u] * F];
        #pragma unroll
        for (int j = 0; j < 8; j++) {
            #pragma unroll
            for (int u = 0; u < 8; u++)
                acc[j] += v[u] * bf2f((ushort)h[u][j]);
        }
    }

    #pragma unroll
    for (int off = FL; off < 64; off <<= 1)
        #pragma unroll
        for (int j = 0; j < 8; j++) acc[j] += __shfl_down(acc[j], off, 64);

    if (ep == 0) {
        #pragma unroll
        for (int j = 0; j < 8; j++) {
            float o = acc[j] + bias[fl * 8 + j];
            if (RELU) o = fmaxf(o, 0.f);
            acc[j] = o;
        }
        if (OUT_BF16) {
            short8 ob;
            #pragma unroll
            for (int j = 0; j < 8; j++) ob[j] = (short)f2bf(acc[j]);
            *(short8*)((ushort*)out + (size_t)r * F + fl * 8) = ob;
        } else {
            float* of = (float*)out + (size_t)r * F + fl * 8;
            *(float4*)&of[0] = make_float4(acc[0], acc[1], acc[2], acc[3]);
            *(float4*)&of[4] = make_float4(acc[4], acc[5], acc[6], acc[7]);
        }
    }
}

// ---------------- launch ----------------

extern "C" void kernel_launch(void* const* d_in, const int* in_sizes, int n_in,
                              void* d_out, int out_size, void* d_ws, size_t ws_size,
                              hipStream_t stream) {
    const float* x    = (const float*)d_in[0];
    const float* av   = (const float*)d_in[1];
    const int*   rows = (const int*)d_in[2];
    const int*   cols = (const int*)d_in[3];
    const float* W1   = (const float*)d_in[4];
    const float* b1   = (const float*)d_in[5];
    const float* W2   = (const float*)d_in[6];
    const float* b2   = (const float*)d_in[7];
    const float* W3   = (const float*)d_in[8];
    const float* b3   = (const float*)d_in[9];
    float* out = (float*)d_out;

    const int N = N_NODES;

    char* p = (char*)d_ws;
    auto carve = [&](size_t bytes) {
        void* q = (void*)p;
        p += (bytes + 255) & ~(size_t)255;
        return q;
    };
    ushort* bufG = (ushort*)carve((size_t)N * 256 * 2);
    ushort* bufH = (ushort*)carve((size_t)N * 256 * 2);
    ushort* Wt1  = (ushort*)carve((size_t)256 * 256 * 2);
    ushort* Wt2  = (ushort*)carve((size_t)256 * 256 * 2);
    ushort* Wt3  = (ushort*)carve((size_t)128 * 256 * 2);
    int*    cnt  = (int*)carve((size_t)N * 4);
    int2*   cv   = (int2*)carve(((size_t)N * ELLCAP + 128) * 8);  // +tail pad

    hipMemsetAsync(cnt, 0, (size_t)N * 4, stream);

    // transpose + ELL build fused (both LDS-free -> full occupancy)
    transpose_ell_kernel<<<TRB + ELLB, 256, 0, stream>>>(
        W1, W2, W3, Wt1, Wt2, Wt3, rows, cols, av, cnt, cv);

    // layer-1 gemm standalone: 782 blocks @ 48KB LDS = one residency pass
    gemm_bf16_kernel<true><<<dim3(391, 2), 256, 0, stream>>>(x, Wt1, bufG, N, 256);

    int spmm_blocks = (N + 3) / 4;
    spmm_kernel<256, true, true><<<spmm_blocks, 256, 0, stream>>>(bufG, cnt, cv, b1, bufH, N);
    gemm_bf16_kernel<false><<<dim3(391, 2), 256, 0, stream>>>(bufH, Wt2, bufG, N, 256);
    spmm_kernel<256, true, true><<<spmm_blocks, 256, 0, stream>>>(bufG, cnt, cv, b2, bufH, N);
    gemm_bf16_kernel<false><<<dim3(391, 1), 256, 0, stream>>>(bufH, Wt3, bufG, N, 128);
    spmm_kernel<128, false, false><<<spmm_blocks, 256, 0, stream>>>(bufG, cnt, cv, b3, out, N);
}

// Round 5
// 360.201 us; speedup vs baseline: 1.0964x; 1.0056x over previous
//
#include <hip/hip_runtime.h>
#include <hip/hip_fp16.h>

// GCN R8: (1) cv packed to 4B (col<<16 | fp16(val)) -> L2-resident, kills
// scatter write amplification. (2) x pre-cast to bf16 inside the prep
// kernel (idle-BW blocks beside the latency-bound ELL atomics). (3) GEMMs
// restructured to 64-row x N-col tiles: A staged once per block (halves A
// traffic), 4 blocks/CU @ 40KB LDS, uniform bf16 A. SpMM reads packed cv.

#define N_NODES 50000
#define N_EDGES 800000
#define KDIM 256
#define BK 32
#define ELLCAP 64            // max degree: Poisson(16) tail ~ e^-125, safe
#define ELLB 391             // 391*256*8 >= 800000 edges (8 edges/thread)
#define XCB 3125             // x-cast blocks: 3125*256*16 = 12.8M elems
#define TRB 640              // transpose blocks: 640*256 = 163840 ids

typedef __attribute__((ext_vector_type(8))) short short8;
typedef __attribute__((ext_vector_type(4))) float f32x4;

__device__ __forceinline__ ushort f2bf(float f) {
    union { float f; unsigned u; } x; x.f = f;
    unsigned r = x.u + 0x7fffu + ((x.u >> 16) & 1u);  // RTN-even
    return (ushort)(r >> 16);
}
__device__ __forceinline__ float bf2f(ushort u) {
    union { unsigned u; float f; } x; x.u = ((unsigned)u) << 16;
    return x.f;
}

// async global->LDS, 16B per lane. LDS dest must be wave-uniform base
// (HW adds lane*16); global src is per-lane.
__device__ __forceinline__ void gld_lds16(const void* g, void* l) {
    __builtin_amdgcn_global_load_lds(
        (const __attribute__((address_space(1))) void*)g,
        (__attribute__((address_space(3))) void*)l, 16, 0, 0);
}

// ---------------- prep: ELL build + x->bf16 cast + weight transposes ------
// blocks [0,ELLB): 8 edges/thread, atomicAdd + 4B packed scatter.
// blocks [ELLB, ELLB+XCB): cast 16 floats/thread x -> bufX bf16.
// blocks [ELLB+XCB, +TRB): Wt[n*256+k] = bf16(W[k*N+n]) for W1/W2/W3.
__global__ __launch_bounds__(256) void prep_kernel(
        const float* __restrict__ W1, const float* __restrict__ W2,
        const float* __restrict__ W3, ushort* __restrict__ Wt1,
        ushort* __restrict__ Wt2, ushort* __restrict__ Wt3,
        const int* __restrict__ rows, const int* __restrict__ cols,
        const float* __restrict__ vals, int* __restrict__ cnt,
        unsigned* __restrict__ cvp, const float* __restrict__ x,
        ushort* __restrict__ bufX) {
    int b = blockIdx.x;
    if (b < ELLB) {
        int e0 = (b * 256 + threadIdx.x) * 8;
        if (e0 < N_EDGES) {           // N_EDGES % 8 == 0: full oct or skip
            int4 ra = *(const int4*)&rows[e0];
            int4 rb = *(const int4*)&rows[e0 + 4];
            int4 ca = *(const int4*)&cols[e0];
            int4 cb = *(const int4*)&cols[e0 + 4];
            float4 va = *(const float4*)&vals[e0];
            float4 vb = *(const float4*)&vals[e0 + 4];
            int   r[8] = {ra.x, ra.y, ra.z, ra.w, rb.x, rb.y, rb.z, rb.w};
            int   c[8] = {ca.x, ca.y, ca.z, ca.w, cb.x, cb.y, cb.z, cb.w};
            float v[8] = {va.x, va.y, va.z, va.w, vb.x, vb.y, vb.z, vb.w};
            #pragma unroll
            for (int u = 0; u < 8; u++) {
                int p = atomicAdd(&cnt[r[u]], 1);
                unsigned pk = ((unsigned)c[u] << 16) |
                              (unsigned)__half_as_ushort(__float2half_rn(v[u]));
                cvp[(r[u] << 6) + p] = pk;
            }
        }
    } else if (b < ELLB + XCB) {
        int base = ((b - ELLB) * 256 + threadIdx.x) * 16;  // exact coverage
        float4 f0 = *(const float4*)&x[base];
        float4 f1 = *(const float4*)&x[base + 4];
        float4 f2 = *(const float4*)&x[base + 8];
        float4 f3 = *(const float4*)&x[base + 12];
        short8 o0, o1;
        o0[0] = (short)f2bf(f0.x); o0[1] = (short)f2bf(f0.y);
        o0[2] = (short)f2bf(f0.z); o0[3] = (short)f2bf(f0.w);
        o0[4] = (short)f2bf(f1.x); o0[5] = (short)f2bf(f1.y);
        o0[6] = (short)f2bf(f1.z); o0[7] = (short)f2bf(f1.w);
        o1[0] = (short)f2bf(f2.x); o1[1] = (short)f2bf(f2.y);
        o1[2] = (short)f2bf(f2.z); o1[3] = (short)f2bf(f2.w);
        o1[4] = (short)f2bf(f3.x); o1[5] = (short)f2bf(f3.y);
        o1[6] = (short)f2bf(f3.z); o1[7] = (short)f2bf(f3.w);
        *(short8*)&bufX[base] = o0;
        *(short8*)&bufX[base + 8] = o1;
    } else {
        int id = (b - ELLB - XCB) * 256 + threadIdx.x;
        if (id < 65536) {
            int n = id >> 8, k = id & 255;
            Wt1[n * 256 + k] = f2bf(W1[k * 256 + n]);
        } else if (id < 131072) {
            int i = id - 65536, n = i >> 8, k = i & 255;
            Wt2[n * 256 + k] = f2bf(W2[k * 256 + n]);
        } else {
            int i = id - 131072, n = i >> 8, k = i & 255;
            Wt3[n * 256 + k] = f2bf(W3[k * 128 + n]);
        }
    }
}

// ---------------- GEMM: C[M,N] = A[M,256] @ Wt[N,256]^T, bf16 in/out ------
// 64-row x N-col tile, N/64 waves (threads = N), BK=32, dbuf, 16x16x32 MFMA.
// A staged ONCE per block (shared by all col-waves). Frag-major 16B
// granules: slot g holds src[row0 + (g>>6)*16 + (g&15)][k0 + ((g&63)>>4)*8
// ..+8) so fragment reads are 64-lane-contiguous ds_read_b128 (0 conflicts).
// LDS: A dbuf 2x4KB + B dbuf 2x(N*64B) = 40KB (N=256) / 24KB (N=128).

template <int N>
__global__ __launch_bounds__(N, 4) void gemm_rows_kernel(
        const ushort* __restrict__ A, const ushort* __restrict__ Wt,
        ushort* __restrict__ C, int M) {
    __shared__ char smem[8192 + 2 * N * 64];

    int t = threadIdx.x;
    int lane = t & 63;
    int w = t >> 6;
    int row0 = blockIdx.x * 64;
    int wn = w * 64;
    int q = lane >> 4, mi = lane & 15;

    auto stageA = [&](int bi, int k0) {
        char* dst = smem + bi * 4096;
        #pragma unroll
        for (int i = 0; i < 256 / N; i++) {
            int g = i * N + t;          // granule 0..255
            int row = row0 + ((g >> 6) << 4) + (g & 15);
            if (row >= M) row = M - 1;
            const ushort* src = A + (size_t)row * KDIM + k0 + (((g & 63) >> 4) << 3);
            gld_lds16(src, dst + (i * N + w * 64) * 16);
        }
    };
    auto stageB = [&](int bi, int k0) {
        char* dst = smem + 8192 + bi * (N * 64);
        #pragma unroll
        for (int i = 0; i < 4; i++) {   // N*4 granules / N threads
            int g = i * N + t;
            int col = ((g >> 6) << 4) + (g & 15);
            const ushort* src = Wt + (size_t)col * KDIM + k0 + (((g & 63) >> 4) << 3);
            gld_lds16(src, dst + (i * N + w * 64) * 16);
        }
    };

    f32x4 acc[4][4];
    #pragma unroll
    for (int i = 0; i < 4; i++)
        #pragma unroll
        for (int j = 0; j < 4; j++) acc[i][j] = (f32x4)0.f;

    stageA(0, 0);
    stageB(0, 0);
    __syncthreads();

    #pragma unroll
    for (int kt = 0; kt < 8; kt++) {
        int cur = kt & 1;
        if (kt < 7) {                   // prefetch flies under ds_read+MFMA
            stageA(cur ^ 1, (kt + 1) * BK);
            stageB(cur ^ 1, (kt + 1) * BK);
        }
        char* Ac = smem + cur * 4096;
        char* Bc = smem + 8192 + cur * (N * 64);

        short8 af[4], bfr[4];
        #pragma unroll
        for (int mt = 0; mt < 4; mt++)
            af[mt] = *(const short8*)(Ac + (mt * 64 + lane) * 16);
        #pragma unroll
        for (int nt = 0; nt < 4; nt++)
            bfr[nt] = *(const short8*)(Bc + ((w * 4 + nt) * 64 + lane) * 16);

        #pragma unroll
        for (int mt = 0; mt < 4; mt++)
            #pragma unroll
            for (int nt = 0; nt < 4; nt++)
                acc[mt][nt] = __builtin_amdgcn_mfma_f32_16x16x32_bf16(
                    af[mt], bfr[nt], acc[mt][nt], 0, 0, 0);

        __syncthreads();
    }

    // ---- epilogue: stage C tile (64 x N bf16) in LDS, linear row stores ---
    ushort* Cs = (ushort*)smem;         // 64*N*2 <= smem size
    #pragma unroll
    for (int mt = 0; mt < 4; mt++)
        #pragma unroll
        for (int r = 0; r < 4; r++)
            #pragma unroll
            for (int nt = 0; nt < 4; nt++)
                Cs[(mt * 16 + q * 4 + r) * N + wn + nt * 16 + mi] =
                    f2bf(acc[mt][nt][r]);
    __syncthreads();
    constexpr int C8 = N / 8;           // 16B granules per row
    #pragma unroll
    for (int i = 0; i < 8; i++) {       // 8*N granules = 64*N/8 total
        int idx = i * N + t;
        int rr = idx / C8, gc = idx % C8;
        int grow = row0 + rr;
        if (grow < M)
            *(short8*)&C[(size_t)grow * N + gc * 8] =
                *(const short8*)&Cs[rr * N + gc * 8];
    }
}

// ---------------- SpMM (ELL, packed 4B meta): wave/row, 8-deep gathers ----
// Row r: edges at cvp[r*64 .. r*64+cnt[r]), entry = col<<16 | fp16(val).
// 8 gathers in flight per lane; guards clamp past-nnz slots to col 0/val 0.

template <int F, bool RELU, bool OUT_BF16>
__global__ __launch_bounds__(256) void spmm_kernel(
        const ushort* __restrict__ H, const int* __restrict__ cnt,
        const unsigned* __restrict__ cvp, const float* __restrict__ bias,
        void* __restrict__ out, int nrows) {
    constexpr int FL = F / 8;       // 32 (F=256) / 16 (F=128)
    constexpr int EP = 64 / FL;     // 2 / 4
    constexpr int STEP = EP * 8;    // 16 / 32 edges per iteration
    int wave = threadIdx.x >> 6, lane = threadIdx.x & 63;
    int r = blockIdx.x * 4 + wave;
    if (r >= nrows) return;
    int fl = lane % FL, ep = lane / FL;
    const ushort* Hl = H + fl * 8;

    float acc[8];
    #pragma unroll
    for (int j = 0; j < 8; j++) acc[j] = 0.f;

    int start = r << 6;             // ELLCAP = 64
    int end = start + cnt[r];
    for (int base = start; base < end; base += STEP) {
        int e0 = base + ep * 8;     // 32B-aligned into cvp
        uint4 ma = *(const uint4*)&cvp[e0];
        uint4 mb = *(const uint4*)&cvp[e0 + 4];
        unsigned mw[8] = {ma.x, ma.y, ma.z, ma.w, mb.x, mb.y, mb.z, mb.w};
        int   c[8];
        float v[8];
        #pragma unroll
        for (int u = 0; u < 8; u++) {
            bool ok = (e0 + u < end);
            c[u] = ok ? (int)(mw[u] >> 16) : 0;
            v[u] = ok ? __half2float(__ushort_as_half((ushort)mw[u])) : 0.f;
        }
        short8 h[8];
        #pragma unroll
        for (int u = 0; u < 8; u++)
            h[u] = *(const short8*)&Hl[(size_t)c[u] * F];
        #pragma unroll
        for (int j = 0; j < 8; j++) {
            #pragma unroll
            for (int u = 0; u < 8; u++)
                acc[j] += v[u] * bf2f((ushort)h[u][j]);
        }
    }

    #pragma unroll
    for (int off = FL; off < 64; off <<= 1)
        #pragma unroll
        for (int j = 0; j < 8; j++) acc[j] += __shfl_down(acc[j], off, 64);

    if (ep == 0) {
        #pragma unroll
        for (int j = 0; j < 8; j++) {
            float o = acc[j] + bias[fl * 8 + j];
            if (RELU) o = fmaxf(o, 0.f);
            acc[j] = o;
        }
        if (OUT_BF16) {
            short8 ob;
            #pragma unroll
            for (int j = 0; j < 8; j++) ob[j] = (short)f2bf(acc[j]);
            *(short8*)((ushort*)out + (size_t)r * F + fl * 8) = ob;
        } else {
            float* of = (float*)out + (size_t)r * F + fl * 8;
            *(float4*)&of[0] = make_float4(acc[0], acc[1], acc[2], acc[3]);
            *(float4*)&of[4] = make_float4(acc[4], acc[5], acc[6], acc[7]);
        }
    }
}

// ---------------- launch ----------------

extern "C" void kernel_launch(void* const* d_in, const int* in_sizes, int n_in,
                              void* d_out, int out_size, void* d_ws, size_t ws_size,
                              hipStream_t stream) {
    const float* x    = (const float*)d_in[0];
    const float* av   = (const float*)d_in[1];
    const int*   rows = (const int*)d_in[2];
    const int*   cols = (const int*)d_in[3];
    const float* W1   = (const float*)d_in[4];
    const float* b1   = (const float*)d_in[5];
    const float* W2   = (const float*)d_in[6];
    const float* b2   = (const float*)d_in[7];
    const float* W3   = (const float*)d_in[8];
    const float* b3   = (const float*)d_in[9];
    float* out = (float*)d_out;

    const int N = N_NODES;

    char* p = (char*)d_ws;
    auto carve = [&](size_t bytes) {
        void* q = (void*)p;
        p += (bytes + 255) & ~(size_t)255;
        return q;
    };
    ushort*   bufG = (ushort*)carve((size_t)N * 256 * 2);
    ushort*   bufH = (ushort*)carve((size_t)N * 256 * 2);
    ushort*   Wt1  = (ushort*)carve((size_t)256 * 256 * 2);
    ushort*   Wt2  = (ushort*)carve((size_t)256 * 256 * 2);
    ushort*   Wt3  = (ushort*)carve((size_t)128 * 256 * 2);
    int*      cnt  = (int*)carve((size_t)N * 4);
    unsigned* cvp  = (unsigned*)carve(((size_t)N * ELLCAP + 128) * 4);

    hipMemsetAsync(cnt, 0, (size_t)N * 4, stream);

    // ELL build + x cast (into bufH) + weight transposes, one fat kernel
    prep_kernel<<<ELLB + XCB + TRB, 256, 0, stream>>>(
        W1, W2, W3, Wt1, Wt2, Wt3, rows, cols, av, cnt, cvp, x, bufH);

    int spmm_blocks = (N + 3) / 4;
    gemm_rows_kernel<256><<<782, 256, 0, stream>>>(bufH, Wt1, bufG, N);
    spmm_kernel<256, true, true><<<spmm_blocks, 256, 0, stream>>>(bufG, cnt, cvp, b1, bufH, N);
    gemm_rows_kernel<256><<<782, 256, 0, stream>>>(bufH, Wt2, bufG, N);
    spmm_kernel<256, true, true><<<spmm_blocks, 256, 0, stream>>>(bufG, cnt, cvp, b2, bufH, N);
    gemm_rows_kernel<128><<<782, 128, 0, stream>>>(bufH, Wt3, bufG, N);
    spmm_kernel<128, false, false><<<spmm_blocks, 256, 0, stream>>>(bufG, cnt, cvp, b3, out, N);
}